// Round 2
// baseline (655.882 us; speedup 1.0000x reference)
//
#include <hip/hip_runtime.h>
#include <math.h>

typedef __attribute__((ext_vector_type(8))) short bf16x8;
typedef __attribute__((ext_vector_type(4))) short bf16x4;
typedef __attribute__((ext_vector_type(4))) float f32x4;

#define RB      96      // rows per block (32 triples; 48 per wave = 16 triples)
#define THREADS 128     // 2 waves
#define LSTR    80      // LDS row stride in bf16 elems (160B -> 16B-aligned rows, bank-rotated)

__device__ __forceinline__ unsigned short f2b(float f) {   // fp32 -> bf16 RNE
    union { float f; unsigned int u; } x; x.f = f;
    unsigned int r = x.u + 0x7FFFu + ((x.u >> 16) & 1u);
    return (unsigned short)(r >> 16);
}
__device__ __forceinline__ float b2f(unsigned short h) {
    union { unsigned int u; float f; } x; x.u = ((unsigned int)h) << 16;
    return x.f;
}

// ---- prep: W1 -> W1T bf16 [n=128][k=64], W2 -> W2T bf16 [n=64][k=64], softmax(edge_attn)
// W1cat[k][n] = n<64 ? W1[k][n] : W1[64+k][n-64]; stored k-contiguous per n for 16B b-frag loads.
__global__ void prep_k(const float* __restrict__ W1, const float* __restrict__ W2,
                       const float* __restrict__ ea, unsigned short* __restrict__ w1t,
                       unsigned short* __restrict__ w2t, float* __restrict__ attn)
{
    int gid = blockIdx.x * 256 + threadIdx.x;
    if (gid < 128 * 64) {
        int n = gid >> 6, k = gid & 63;
        float v = (n < 64) ? W1[k * 64 + n] : W1[(64 + k) * 64 + (n - 64)];
        w1t[gid] = f2b(v);
    } else if (gid < 128 * 64 + 64 * 64) {
        int idx = gid - 128 * 64;
        int n = idx >> 6, k = idx & 63;
        w2t[idx] = f2b(W2[k * 64 + n]);
    }
    if (gid < 9) {
        int i = gid / 3, j = gid % 3;
        float e0 = ea[i*3+0], e1 = ea[i*3+1], e2 = ea[i*3+2];
        float mx = fmaxf(e0, fmaxf(e1, e2));
        float d = expf(e0-mx) + expf(e1-mx) + expf(e2-mx);
        attn[gid] = expf(ea[i*3+j] - mx) / d;
    }
}

__global__ __launch_bounds__(THREADS, 2)
void edge_mfma(const float* __restrict__ nodes,
               const unsigned short* __restrict__ w1t,
               const unsigned short* __restrict__ w2t,
               const float* __restrict__ attn9,
               const float* __restrict__ b1,
               const float* __restrict__ b2,
               float* __restrict__ out)
{
    __shared__ unsigned short us[RB * LSTR];   // X tile -> U -> G (serial reuse)
    __shared__ unsigned short vs[RB * LSTR];   // V

    const int t = threadIdx.x;
    const int lane = t & 63, wave = t >> 6;
    const int r16 = lane & 15, q = lane >> 4;
    const int wrow = wave * 48;
    const long base = (long)blockIdx.x * (RB * 64);

    // ---- phase 0: stage X -> us as bf16 (coalesced float4 reads) ----
    {
        const float4* src = (const float4*)(nodes + base);
        #pragma unroll
        for (int it = 0; it < 12; ++it) {
            int idx = t + it * THREADS;           // 1536 float4
            float4 v = src[idx];
            int row = idx >> 4, c4 = (idx & 15) << 2;
            bf16x4 p;
            p[0] = (short)f2b(v.x); p[1] = (short)f2b(v.y);
            p[2] = (short)f2b(v.z); p[3] = (short)f2b(v.w);
            *(bf16x4*)&us[row * LSTR + c4] = p;
        }
    }
    __syncthreads();

    // ---- phase 0b: A-frags (lane holds row=r16, k = ks*32 + q*8 + e, contiguous 16B) ----
    bf16x8 afr[3][2];
    #pragma unroll
    for (int mt = 0; mt < 3; ++mt)
        #pragma unroll
        for (int ks = 0; ks < 2; ++ks)
            afr[mt][ks] = *(const bf16x8*)&us[(wrow + mt*16 + r16) * LSTR + ks*32 + q*8];
    __syncthreads();   // us now reusable for U

    // ---- phase 1: GEMM1  [U|V] = X @ W1cat ----
    {
        bf16x8 bfr[8][2];
        #pragma unroll
        for (int nt = 0; nt < 8; ++nt)
            #pragma unroll
            for (int ks = 0; ks < 2; ++ks)
                bfr[nt][ks] = *(const bf16x8*)&w1t[(nt*16 + r16) * 64 + ks*32 + q*8];
        #pragma unroll
        for (int nt = 0; nt < 8; ++nt) {
            unsigned short* dst = (nt < 4) ? us : vs;
            const int c0 = (nt & 3) * 16;
            #pragma unroll
            for (int mt = 0; mt < 3; ++mt) {
                f32x4 acc = {0.f, 0.f, 0.f, 0.f};
                acc = __builtin_amdgcn_mfma_f32_16x16x32_bf16(afr[mt][0], bfr[nt][0], acc, 0, 0, 0);
                acc = __builtin_amdgcn_mfma_f32_16x16x32_bf16(afr[mt][1], bfr[nt][1], acc, 0, 0, 0);
                #pragma unroll
                for (int r = 0; r < 4; ++r)   // C: row=(lane>>4)*4+r, col=lane&15
                    dst[(wrow + mt*16 + q*4 + r) * LSTR + c0 + r16] = f2b(acc[r]);
            }
        }
    }
    __syncthreads();

    // ---- phase 2: g = sum_j a_ij * gelu(u_i + v_j + b1), all in regs ----
    float g[6][8];
    #pragma unroll
    for (int it = 0; it < 6; ++it) {
        int task = t + it * THREADS;              // 768 tasks: row x 8-col chunk
        int row = task >> 3, c8 = (task & 7) * 8;
        int i = row % 3;
        int trip = row - i;
        float aw0 = attn9[i*3+0], aw1 = attn9[i*3+1], aw2 = attn9[i*3+2];
        bf16x8 uvv = *(const bf16x8*)&us[row*LSTR + c8];
        bf16x8 v0 = *(const bf16x8*)&vs[(trip+0)*LSTR + c8];
        bf16x8 v1 = *(const bf16x8*)&vs[(trip+1)*LSTR + c8];
        bf16x8 v2 = *(const bf16x8*)&vs[(trip+2)*LSTR + c8];
        float4 b1a = *(const float4*)(b1 + c8);
        float4 b1b = *(const float4*)(b1 + c8 + 4);
        float b1v[8] = {b1a.x,b1a.y,b1a.z,b1a.w,b1b.x,b1b.y,b1b.z,b1b.w};
        #pragma unroll
        for (int e = 0; e < 8; ++e) {
            float uu = b2f((unsigned short)uvv[e]) + b1v[e];
            float s0 = uu + b2f((unsigned short)v0[e]);
            float s1 = uu + b2f((unsigned short)v1[e]);
            float s2 = uu + b2f((unsigned short)v2[e]);
            float g0 = 0.5f * s0 * (1.f + erff(s0 * 0.70710678118654752f));
            float g1 = 0.5f * s1 * (1.f + erff(s1 * 0.70710678118654752f));
            float g2 = 0.5f * s2 * (1.f + erff(s2 * 0.70710678118654752f));
            g[it][e] = aw0*g0 + aw1*g1 + aw2*g2;
        }
    }
    __syncthreads();                              // all u,v reads done
    #pragma unroll
    for (int it = 0; it < 6; ++it) {              // G (bf16) overwrites U
        int task = t + it * THREADS;
        int row = task >> 3, c8 = (task & 7) * 8;
        bf16x8 p;
        #pragma unroll
        for (int e = 0; e < 8; ++e) p[e] = (short)f2b(g[it][e]);
        *(bf16x8*)&us[row*LSTR + c8] = p;
    }
    __syncthreads();

    // ---- phase 3: GEMM2  out = G @ W2 + b2 ----
    {
        bf16x8 gfr[3][2];
        #pragma unroll
        for (int mt = 0; mt < 3; ++mt)
            #pragma unroll
            for (int ks = 0; ks < 2; ++ks)
                gfr[mt][ks] = *(const bf16x8*)&us[(wrow + mt*16 + r16)*LSTR + ks*32 + q*8];
        #pragma unroll
        for (int nt = 0; nt < 4; ++nt) {
            bf16x8 w0  = *(const bf16x8*)&w2t[(nt*16 + r16)*64 + q*8];
            bf16x8 w1f = *(const bf16x8*)&w2t[(nt*16 + r16)*64 + 32 + q*8];
            float b2v = b2[nt*16 + r16];
            #pragma unroll
            for (int mt = 0; mt < 3; ++mt) {
                f32x4 acc = {0.f, 0.f, 0.f, 0.f};
                acc = __builtin_amdgcn_mfma_f32_16x16x32_bf16(gfr[mt][0], w0,  acc, 0, 0, 0);
                acc = __builtin_amdgcn_mfma_f32_16x16x32_bf16(gfr[mt][1], w1f, acc, 0, 0, 0);
                #pragma unroll
                for (int r = 0; r < 4; ++r)   // lanes 0-15 = 64B contiguous per row-group: full segments
                    out[base + (long)(wrow + mt*16 + q*4 + r)*64 + nt*16 + r16] = acc[r] + b2v;
            }
        }
    }
}

extern "C" void kernel_launch(void* const* d_in, const int* in_sizes, int n_in,
                              void* d_out, int out_size, void* d_ws, size_t ws_size,
                              hipStream_t stream)
{
    const float* nodes = (const float*)d_in[0];
    const float* W1    = (const float*)d_in[1];
    const float* b1    = (const float*)d_in[2];
    const float* W2    = (const float*)d_in[3];
    const float* b2    = (const float*)d_in[4];
    const float* ea    = (const float*)d_in[5];
    float* out = (float*)d_out;

    unsigned short* w1t = (unsigned short*)d_ws;          // 128*64 bf16 = 16 KB
    unsigned short* w2t = w1t + 128 * 64;                 // 64*64 bf16 = 8 KB
    float* attn = (float*)(w2t + 64 * 64);                // 9 floats

    prep_k<<<48, 256, 0, stream>>>(W1, W2, ea, w1t, w2t, attn);

    const int total_rows = out_size / 64;                 // 786432
    const int grid = total_rows / RB;                     // 8192
    edge_mfma<<<grid, THREADS, 0, stream>>>(nodes, w1t, w2t, attn, b1, b2, out);
}

// Round 3
// 213.675 us; speedup vs baseline: 3.0695x; 3.0695x over previous
//
#include <hip/hip_runtime.h>
#include <math.h>

typedef __attribute__((ext_vector_type(8))) short bf16x8;
typedef __attribute__((ext_vector_type(4))) float f32x4;

#define THREADS 256
#define ITERS   4
#define GRID    1024        // 1024 blocks * 4 iters * 64 batches = 262144 = B
#define WSTR    68          // LDS row stride (shorts): 136B -> conflict-free frag reads

__device__ __forceinline__ unsigned short f2b(float f) {   // fp32 -> bf16 RNE
    union { float f; unsigned int u; } x; x.f = f;
    unsigned int r = x.u + 0x7FFFu + ((x.u >> 16) & 1u);
    return (unsigned short)(r >> 16);
}

// prep: W1cat -> ws padded [128][WSTR] bf16 (k-contiguous per output col n),
//       W2    -> ws+8704   [64][WSTR] bf16, softmax(edge_attn) -> 9 floats.
__global__ void prep_k(const float* __restrict__ W1, const float* __restrict__ W2,
                       const float* __restrict__ ea, unsigned short* __restrict__ wsw,
                       float* __restrict__ attn)
{
    int gid = blockIdx.x * 256 + threadIdx.x;
    if (gid < 128 * 64) {
        int n = gid >> 6, k = gid & 63;
        float v = (n < 64) ? W1[k * 64 + n] : W1[(64 + k) * 64 + (n - 64)];
        wsw[n * WSTR + k] = f2b(v);
    } else if (gid < 12288) {
        int idx = gid - 8192;
        int n = idx >> 6, k = idx & 63;
        wsw[8704 + n * WSTR + k] = f2b(W2[k * 64 + n]);
    }
    if (gid < 9) {
        int i = gid / 3, j = gid % 3;
        float e0 = ea[i*3+0], e1 = ea[i*3+1], e2 = ea[i*3+2];
        float mx = fmaxf(e0, fmaxf(e1, e2));
        float d = expf(e0-mx) + expf(e1-mx) + expf(e2-mx);
        attn[gid] = expf(ea[i*3+j] - mx) / d;
    }
}

__global__ __launch_bounds__(THREADS, 4)
void edge_mfma2(const float* __restrict__ nodes,
                const unsigned short* __restrict__ wsw,
                const float* __restrict__ attn9,
                const float* __restrict__ b1,
                const float* __restrict__ b2,
                float* __restrict__ out)
{
    // LDS: w1p [128][WSTR] | w2p [64][WSTR] | G [4 waves][16][WSTR]
    __shared__ __align__(16) unsigned short lds[17408];   // 34816 B -> 4 blocks/CU
    unsigned short* w1p = lds;
    unsigned short* w2p = lds + 8704;

    const int t = threadIdx.x;
    const int lane = t & 63, wave = t >> 6;
    const int q = lane >> 4, r16 = lane & 15;
    unsigned short* Gw = lds + 13056 + wave * 1088;       // wave-private [16][WSTR]

    // ---- stage weights HBM -> LDS once per block (13056 shorts = 1632 x 16B) ----
    {
        const ulonglong2* src = (const ulonglong2*)wsw;
        ulonglong2* dst = (ulonglong2*)lds;
        #pragma unroll
        for (int i = 0; i < 7; ++i) {
            int idx = t + i * THREADS;
            if (idx < 1632) dst[idx] = src[idx];
        }
    }
    __syncthreads();   // only barrier in the kernel

    // per-lane A-row mapping: padded row r16 -> batch bA, row-in-batch iA (dummy i=3 -> 0)
    const int bA = r16 >> 2;
    const int iA = ((r16 & 3) == 3) ? 0 : (r16 & 3);

    // uniform attn weights (scalar loads -> SGPRs)
    float aw[3][3];
    #pragma unroll
    for (int i = 0; i < 3; ++i)
        #pragma unroll
        for (int j = 0; j < 3; ++j) aw[i][j] = attn9[i*3+j];

    float b1c[4], b2c[4];
    #pragma unroll
    for (int nt = 0; nt < 4; ++nt) { b1c[nt] = b1[nt*16 + r16]; b2c[nt] = b2[nt*16 + r16]; }

    const float inv_sqrt2 = 0.70710678118654752f;

    for (int itr = 0; itr < ITERS; ++itr) {
        const int batch0 = (blockIdx.x * ITERS + itr) * 64 + wave * 16;
        #pragma unroll
        for (int mt = 0; mt < 4; ++mt) {
            // ---- X -> A-frags (global, no LDS). k = ks*32 + q*8 + e ----
            const long rowA = ((long)(batch0 + mt*4 + bA)) * 3 + iA;
            const float* xp = nodes + rowA * 64 + q * 8;
            f32x4 x0 = __builtin_nontemporal_load((const f32x4*)(xp));
            f32x4 x1 = __builtin_nontemporal_load((const f32x4*)(xp + 4));
            f32x4 x2 = __builtin_nontemporal_load((const f32x4*)(xp + 32));
            f32x4 x3 = __builtin_nontemporal_load((const f32x4*)(xp + 36));
            bf16x8 afr0, afr1;
            #pragma unroll
            for (int e = 0; e < 4; ++e) {
                afr0[e]   = (short)f2b(x0[e]); afr0[4+e] = (short)f2b(x1[e]);
                afr1[e]   = (short)f2b(x2[e]); afr1[4+e] = (short)f2b(x3[e]);
            }

            // ---- GEMM1: lane gets u[i], v[j] of batch q at col nt*16+r16 ----
            f32x4 aU[4], aV[4];
            #pragma unroll
            for (int nt = 0; nt < 4; ++nt) {
                f32x4 z = {0.f, 0.f, 0.f, 0.f};
                bf16x8 bu0 = *(const bf16x8*)&w1p[(nt*16 + r16) * WSTR + q*8];
                bf16x8 bu1 = *(const bf16x8*)&w1p[(nt*16 + r16) * WSTR + 32 + q*8];
                z = __builtin_amdgcn_mfma_f32_16x16x32_bf16(afr0, bu0, z, 0, 0, 0);
                z = __builtin_amdgcn_mfma_f32_16x16x32_bf16(afr1, bu1, z, 0, 0, 0);
                aU[nt] = z;
                f32x4 y = {0.f, 0.f, 0.f, 0.f};
                bf16x8 bv0 = *(const bf16x8*)&w1p[((nt+4)*16 + r16) * WSTR + q*8];
                bf16x8 bv1 = *(const bf16x8*)&w1p[((nt+4)*16 + r16) * WSTR + 32 + q*8];
                y = __builtin_amdgcn_mfma_f32_16x16x32_bf16(afr0, bv0, y, 0, 0, 0);
                y = __builtin_amdgcn_mfma_f32_16x16x32_bf16(afr1, bv1, y, 0, 0, 0);
                aV[nt] = y;
            }

            // ---- lane-local gelu mix: g[i] = sum_j a_ij * gelu(u_i + v_j + b1) ----
            #pragma unroll
            for (int nt = 0; nt < 4; ++nt) {
                float u0 = aU[nt][0] + b1c[nt];
                float u1 = aU[nt][1] + b1c[nt];
                float u2 = aU[nt][2] + b1c[nt];
                float gg0 = 0.f, gg1 = 0.f, gg2 = 0.f;
                #pragma unroll
                for (int j = 0; j < 3; ++j) {
                    float vj = aV[nt][j];
                    float s0 = u0 + vj, s1 = u1 + vj, s2 = u2 + vj;
                    float gl0 = 0.5f * s0 * (1.f + erff(s0 * inv_sqrt2));
                    float gl1 = 0.5f * s1 * (1.f + erff(s1 * inv_sqrt2));
                    float gl2 = 0.5f * s2 * (1.f + erff(s2 * inv_sqrt2));
                    gg0 = fmaf(aw[0][j], gl0, gg0);
                    gg1 = fmaf(aw[1][j], gl1, gg1);
                    gg2 = fmaf(aw[2][j], gl2, gg2);
                }
                Gw[(q*4 + 0) * WSTR + nt*16 + r16] = f2b(gg0);
                Gw[(q*4 + 1) * WSTR + nt*16 + r16] = f2b(gg1);
                Gw[(q*4 + 2) * WSTR + nt*16 + r16] = f2b(gg2);
            }
            // same-wave DS ordering: writes above complete before reads below (in-order DS pipe);
            // compiler inserts lgkmcnt for the register dependency.

            // ---- GEMM2: A = G (wave-private LDS), B = W2; store with +b2 ----
            bf16x8 gfr0 = *(const bf16x8*)&Gw[r16 * WSTR + q*8];
            bf16x8 gfr1 = *(const bf16x8*)&Gw[r16 * WSTR + 32 + q*8];
            #pragma unroll
            for (int nt = 0; nt < 4; ++nt) {
                f32x4 acc = {0.f, 0.f, 0.f, 0.f};
                bf16x8 wa = *(const bf16x8*)&w2p[(nt*16 + r16) * WSTR + q*8];
                bf16x8 wb = *(const bf16x8*)&w2p[(nt*16 + r16) * WSTR + 32 + q*8];
                acc = __builtin_amdgcn_mfma_f32_16x16x32_bf16(gfr0, wa, acc, 0, 0, 0);
                acc = __builtin_amdgcn_mfma_f32_16x16x32_bf16(gfr1, wb, acc, 0, 0, 0);
                const long ob = ((long)(batch0 + mt*4 + q)) * 3;
                float* op = out + ob * 64 + nt*16 + r16;
                #pragma unroll
                for (int r = 0; r < 3; ++r)
                    __builtin_nontemporal_store(acc[r] + b2c[nt], op + r * 64);
            }
        }
    }
}

extern "C" void kernel_launch(void* const* d_in, const int* in_sizes, int n_in,
                              void* d_out, int out_size, void* d_ws, size_t ws_size,
                              hipStream_t stream)
{
    const float* nodes = (const float*)d_in[0];
    const float* W1    = (const float*)d_in[1];
    const float* b1    = (const float*)d_in[2];
    const float* W2    = (const float*)d_in[3];
    const float* b2    = (const float*)d_in[4];
    const float* ea    = (const float*)d_in[5];
    float* out = (float*)d_out;

    unsigned short* wsw = (unsigned short*)d_ws;          // 13056 shorts padded weights
    float* attn = (float*)(wsw + 13056);                  // 9 floats

    prep_k<<<48, 256, 0, stream>>>(W1, W2, ea, wsw, attn);
    edge_mfma2<<<GRID, THREADS, 0, stream>>>(nodes, wsw, attn, b1, b2, out);
}

// Round 4
// 98.747 us; speedup vs baseline: 6.6421x; 2.1639x over previous
//
#include <hip/hip_runtime.h>
#include <math.h>

typedef __attribute__((ext_vector_type(8))) short bf16x8;
typedef __attribute__((ext_vector_type(4))) float f32x4;

#define WSTR 68     // G-buffer row stride in shorts (136B): conflict-free frag reads

__device__ __forceinline__ unsigned short f2b(float f) {   // fp32 -> bf16 RNE
    union { float f; unsigned int u; } x; x.f = f;
    unsigned int r = x.u + 0x7FFFu + ((x.u >> 16) & 1u);
    return (unsigned short)(r >> 16);
}

// gelu(x) = x*sigmoid(2y), y = 0.7978845608*x*(1+0.044715*x^2)   (tanh-form, hw exp)
// z = 2*log2(e)*y ; sigmoid(2y) = 1 - 1/(1+2^z)
__device__ __forceinline__ float gelu_t(float x) {
    float x2 = x * x;
    float z  = x * fmaf(0.10294324f, x2, 2.3022082f);
    float e  = __builtin_amdgcn_exp2f(z);
    float r  = __builtin_amdgcn_rcpf(1.0f + e);
    return fmaf(x, -r, x);          // x*(1-r)
}

// prep: w1t[n*64+k] = W1cat[k][n]  (n<64: W1top col n, n>=64: W1bot col n-64)
//       w2t[n*64+k] = W2[k][n];  attn = softmax(edge_attn) rows
__global__ void prep_k(const float* __restrict__ W1, const float* __restrict__ W2,
                       const float* __restrict__ ea, unsigned short* __restrict__ w1t,
                       unsigned short* __restrict__ w2t, float* __restrict__ attn)
{
    int gid = blockIdx.x * 256 + threadIdx.x;
    if (gid < 128 * 64) {
        int n = gid >> 6, k = gid & 63;
        float v = (n < 64) ? W1[k * 64 + n] : W1[(64 + k) * 64 + (n - 64)];
        w1t[gid] = f2b(v);
    } else if (gid < 12288) {
        int idx = gid - 8192;
        int n = idx >> 6, k = idx & 63;
        w2t[idx] = f2b(W2[k * 64 + n]);
    }
    if (gid < 9) {
        int i = gid / 3, j = gid % 3;
        float e0 = ea[i*3+0], e1 = ea[i*3+1], e2 = ea[i*3+2];
        float mx = fmaxf(e0, fmaxf(e1, e2));
        float d = expf(e0-mx) + expf(e1-mx) + expf(e2-mx);
        attn[gid] = expf(ea[i*3+j] - mx) / d;
    }
}

__global__ __launch_bounds__(256, 3)
void edge_mfma3(const float* __restrict__ nodes,
                const unsigned short* __restrict__ w1t,
                const unsigned short* __restrict__ w2t,
                const float* __restrict__ attn9,
                const float* __restrict__ b1,
                const float* __restrict__ b2,
                float* __restrict__ out)
{
    __shared__ __align__(16) unsigned short Gs[4 * 16 * WSTR];   // 8704 B total

    const int t = threadIdx.x;
    const int lane = t & 63, wave = t >> 6;
    const int q = lane >> 4, r16 = lane & 15;
    unsigned short* Gw = Gs + wave * 16 * WSTR;                  // wave-private

    // padded row mapping: tile row r16 -> batch bA (of 4), node-row iA (3 = dummy -> 0)
    const int bA = r16 >> 2;
    const int iA = ((r16 & 3) == 3) ? 0 : (r16 & 3);

    // ---- weight fragments: load ONCE into VGPRs (per-lane 16B, L2-hot) ----
    bf16x8 w1f[8][2], w2f[4][2];
    #pragma unroll
    for (int nt = 0; nt < 8; ++nt)
        #pragma unroll
        for (int ks = 0; ks < 2; ++ks)
            w1f[nt][ks] = *(const bf16x8*)&w1t[(nt*16 + r16) * 64 + ks*32 + q*8];
    #pragma unroll
    for (int nt = 0; nt < 4; ++nt)
        #pragma unroll
        for (int ks = 0; ks < 2; ++ks)
            w2f[nt][ks] = *(const bf16x8*)&w2t[(nt*16 + r16) * 64 + ks*32 + q*8];

    // uniform attn weights (scalarized), per-lane bias slices
    float aw[3][3];
    #pragma unroll
    for (int i = 0; i < 3; ++i)
        #pragma unroll
        for (int j = 0; j < 3; ++j) aw[i][j] = attn9[i*3+j];
    float b1c[4], b2c[4];
    #pragma unroll
    for (int nt = 0; nt < 4; ++nt) { b1c[nt] = b1[nt*16 + r16]; b2c[nt] = b2[nt*16 + r16]; }

    const int batch0 = blockIdx.x * 64 + wave * 16;

    #pragma unroll
    for (int mt = 0; mt < 4; ++mt) {
        // ---- X -> A-frags straight from global (k = ks*32 + q*8 + e) ----
        const long rowA = ((long)(batch0 + mt*4 + bA)) * 3 + iA;
        const f32x4* xp = (const f32x4*)(nodes + rowA * 64 + q * 8);
        f32x4 x0 = xp[0], x1 = xp[1], x2v = xp[8], x3 = xp[9];
        bf16x8 afr0, afr1;
        #pragma unroll
        for (int e = 0; e < 4; ++e) {
            afr0[e]   = (short)f2b(x0[e]);  afr0[4+e] = (short)f2b(x1[e]);
            afr1[e]   = (short)f2b(x2v[e]); afr1[4+e] = (short)f2b(x3[e]);
        }

        // ---- GEMM1 + lane-local gelu mix, per 16-col tile ----
        #pragma unroll
        for (int nt = 0; nt < 4; ++nt) {
            f32x4 z = {0.f, 0.f, 0.f, 0.f};
            z = __builtin_amdgcn_mfma_f32_16x16x32_bf16(afr0, w1f[nt][0], z, 0, 0, 0);
            z = __builtin_amdgcn_mfma_f32_16x16x32_bf16(afr1, w1f[nt][1], z, 0, 0, 0);
            f32x4 y = {0.f, 0.f, 0.f, 0.f};
            y = __builtin_amdgcn_mfma_f32_16x16x32_bf16(afr0, w1f[nt+4][0], y, 0, 0, 0);
            y = __builtin_amdgcn_mfma_f32_16x16x32_bf16(afr1, w1f[nt+4][1], y, 0, 0, 0);

            // lane holds batch q: u rows z[0..2], v rows y[0..2], col nt*16+r16
            float u0 = z[0] + b1c[nt], u1 = z[1] + b1c[nt], u2 = z[2] + b1c[nt];
            float gg0 = 0.f, gg1 = 0.f, gg2 = 0.f;
            #pragma unroll
            for (int j = 0; j < 3; ++j) {
                float vj = y[j];
                float gl0 = gelu_t(u0 + vj);
                float gl1 = gelu_t(u1 + vj);
                float gl2 = gelu_t(u2 + vj);
                gg0 = fmaf(aw[0][j], gl0, gg0);
                gg1 = fmaf(aw[1][j], gl1, gg1);
                gg2 = fmaf(aw[2][j], gl2, gg2);
            }
            Gw[(q*4 + 0) * WSTR + nt*16 + r16] = f2b(gg0);
            Gw[(q*4 + 1) * WSTR + nt*16 + r16] = f2b(gg1);
            Gw[(q*4 + 2) * WSTR + nt*16 + r16] = f2b(gg2);
        }
        // same-wave DS ordering: compiler emits lgkmcnt before dependent reads

        // ---- GEMM2: A = G via wave-private LDS transpose, B = W2 in regs ----
        bf16x8 gfr0 = *(const bf16x8*)&Gw[r16 * WSTR + q*8];
        bf16x8 gfr1 = *(const bf16x8*)&Gw[r16 * WSTR + 32 + q*8];
        #pragma unroll
        for (int nt = 0; nt < 4; ++nt) {
            f32x4 acc = {0.f, 0.f, 0.f, 0.f};
            acc = __builtin_amdgcn_mfma_f32_16x16x32_bf16(gfr0, w2f[nt][0], acc, 0, 0, 0);
            acc = __builtin_amdgcn_mfma_f32_16x16x32_bf16(gfr1, w2f[nt][1], acc, 0, 0, 0);
            float* op = out + ((long)(batch0 + mt*4 + q) * 3) * 64 + nt*16 + r16;
            #pragma unroll
            for (int r = 0; r < 3; ++r)
                __builtin_nontemporal_store(acc[r] + b2c[nt], op + r * 64);
        }
    }
}

extern "C" void kernel_launch(void* const* d_in, const int* in_sizes, int n_in,
                              void* d_out, int out_size, void* d_ws, size_t ws_size,
                              hipStream_t stream)
{
    const float* nodes = (const float*)d_in[0];
    const float* W1    = (const float*)d_in[1];
    const float* b1    = (const float*)d_in[2];
    const float* W2    = (const float*)d_in[3];
    const float* b2    = (const float*)d_in[4];
    const float* ea    = (const float*)d_in[5];
    float* out = (float*)d_out;

    unsigned short* w1t = (unsigned short*)d_ws;          // 8192 shorts
    unsigned short* w2t = w1t + 8192;                     // 4096 shorts
    float* attn = (float*)(w2t + 4096);                   // 9 floats

    prep_k<<<48, 256, 0, stream>>>(W1, W2, ea, w1t, w2t, attn);

    const int groups = (out_size / 64) / 3 / 64;          // 4096 blocks of 64 batches
    edge_mfma3<<<groups, 256, 0, stream>>>(nodes, w1t, w2t, attn, b1, b2, out);
}